// Round 8
// baseline (178.052 us; speedup 1.0000x reference)
//
#include <hip/hip_runtime.h>
#include <hip/hip_bf16.h>

// CategorySpecificLinear: out[b,t,h] = sum_d x[b,t,d] * W[cat[b],d,h] + bias[cat[b],h]
// R8: 8-batch records (BM=256), BN=64, 512-thread 8-wave blocks, 45KB LDS ->
// 3 independent blocks/CU (cross-block latency hiding). LDK=36 (conflict-light
// fragment reads). Record sort desc + round-robin XCD deal; all 16 ntiles of a
// record on one XCD. Dist-1 register prefetch + double-buffered LDS + raw
// s_barrier with lgkmcnt-only drain.

#define NCAT 32
#define DIN  1024
#define DH   1024
#define NBATCH 256
#define TT   32
#define NRECPAD 64     // record slots (multiple of 8); sum ceil(cnt/8) <= 60
#define RSTRIDE 12     // ints per record: cat, nb, b0..b7, pad2

#define BM 256
#define BN 64
#define BK 32
#define LDK 36         // LDS row stride in bf16 elems (BK + 4 pad), 18 dwords
#define NITER (DIN / BK)   // 32
#define NTILES (DH / BN)   // 16

typedef __attribute__((ext_vector_type(4))) float f32x4;
typedef __attribute__((ext_vector_type(8))) short bf16x8;
typedef __attribute__((ext_vector_type(4))) short bf16x4;

__device__ inline short f2bf(float f) {
    unsigned u = __builtin_bit_cast(unsigned, f);
    u += 0x7fffu + ((u >> 16) & 1u);
    return (short)(u >> 16);
}

// ---------------------------------------------------------------------------
// Setup: group batches by category into records of <=8, sort by nb desc,
// write to recs[rank]. Rank r runs on XCD r%8 (round-robin deal = LPT-ish).
// ---------------------------------------------------------------------------
__global__ void cat_setup_kernel(const int* __restrict__ cat_ids,
                                 int* __restrict__ recs) {
    __shared__ int cats[NBATCH];
    __shared__ int cnt[NCAT];
    __shared__ int off[NCAT + 1];
    __shared__ int rstart[NCAT + 1];
    __shared__ int blist[NBATCH];
    __shared__ int cbuf[NRECPAD * RSTRIDE];
    __shared__ int nrec_s;
    const int t = threadIdx.x;
    cats[t] = cat_ids[t];
    for (int i = t; i < NRECPAD * RSTRIDE; i += 256) cbuf[i] = 0;
    __syncthreads();
    if (t < NCAT) {
        int c = 0;
        for (int i = 0; i < NBATCH; ++i) c += (cats[i] == t) ? 1 : 0;
        cnt[t] = c;
    }
    __syncthreads();
    if (t == 0) {
        off[0] = 0; rstart[0] = 0;
        for (int c = 0; c < NCAT; ++c) {
            off[c + 1] = off[c] + cnt[c];
            rstart[c + 1] = rstart[c] + (cnt[c] + 7) / 8;
        }
        nrec_s = rstart[NCAT];
    }
    __syncthreads();
    {   // stable scatter: batches grouped by cat
        int c = cats[t], rank = 0;
        for (int i = 0; i < t; ++i) rank += (cats[i] == c) ? 1 : 0;
        blist[off[c] + rank] = t;
    }
    __syncthreads();
    if (t < NCAT) {   // build this cat's records (chunks of 8)
        int base = off[t], rem = cnt[t], k = 0;
        while (rem > 0) {
            int nb = rem < 8 ? rem : 8;
            int* rb = cbuf + (rstart[t] + k) * RSTRIDE;
            rb[0] = t; rb[1] = nb;
            for (int i = 0; i < nb; ++i) rb[2 + i] = blist[base + i];
            for (int i = nb; i < 8; ++i) rb[2 + i] = rb[2];
            base += nb; rem -= nb; ++k;
        }
    }
    __syncthreads();
    for (int i = t; i < NRECPAD * RSTRIDE; i += 256) recs[i] = 0;
    __syncthreads();
    const int nrec = nrec_s;
    if (t < nrec) {   // rank by nb desc (stable), write
        const int mynb = cbuf[t * RSTRIDE + 1];
        int rank = 0;
        for (int i = 0; i < nrec; ++i) {
            const int nbi = cbuf[i * RSTRIDE + 1];
            rank += ((nbi > mynb) || (nbi == mynb && i < t)) ? 1 : 0;
        }
        for (int f = 0; f < RSTRIDE; ++f)
            recs[rank * RSTRIDE + f] = cbuf[t * RSTRIDE + f];
    }
}

// One K-step: convert+stage tile it (predicated), prefetch tile it+1 into the
// same regs, barrier (lgkm-only drain), fragments + 8 MFMA (predicated).
__device__ __forceinline__ void gemm_step(
    f32x4 (&xv)[4], f32x4 (&wv)[4],
    short* xd, short* wd,
    const short* ap, const short* bp,
    const float* xsrc, const float* wsrc,
    bool xact, bool wact, bool mact,
    int wn4, int wk4, int it,
    f32x4 (&acc)[4][2]) {

    if (xact) {
#pragma unroll
        for (int i = 0; i < 4; ++i) {
            bf16x4 q;
            q[0] = f2bf(xv[i][0]);
            q[1] = f2bf(xv[i][1]);
            q[2] = f2bf(xv[i][2]);
            q[3] = f2bf(xv[i][3]);
            *(bf16x4*)(xd + i * 8 * LDK) = q;
        }
    }
    if (wact) {
#pragma unroll
        for (int j = 0; j < 4; ++j) {
            bf16x4 q;
            q[0] = f2bf(wv[0][j]);
            q[1] = f2bf(wv[1][j]);
            q[2] = f2bf(wv[2][j]);
            q[3] = f2bf(wv[3][j]);
            *(bf16x4*)(wd + (wn4 + j) * LDK + wk4) = q;
        }
    }

    if (it + 1 < NITER) {
        const int k0 = (it + 1) * BK;
        if (xact) {
#pragma unroll
            for (int i = 0; i < 4; ++i)
                xv[i] = *(const f32x4*)(xsrc + k0 + (size_t)(i * 8) * DIN);
        }
        if (wact) {
#pragma unroll
            for (int i = 0; i < 4; ++i)
                wv[i] = *(const f32x4*)(wsrc + (size_t)(k0 + i) * DH);
        }
    }

    asm volatile("s_waitcnt lgkmcnt(0)" ::: "memory");
    __builtin_amdgcn_s_barrier();
    asm volatile("" ::: "memory");

    if (mact) {
        bf16x8 af[4], bfr[2];
#pragma unroll
        for (int mi = 0; mi < 4; ++mi)
            af[mi] = *(const bf16x8*)(ap + mi * 16 * LDK);
#pragma unroll
        for (int ni = 0; ni < 2; ++ni)
            bfr[ni] = *(const bf16x8*)(bp + ni * 16 * LDK);
#pragma unroll
        for (int mi = 0; mi < 4; ++mi)
#pragma unroll
            for (int ni = 0; ni < 2; ++ni)
                acc[mi][ni] = __builtin_amdgcn_mfma_f32_16x16x32_bf16(
                    af[mi], bfr[ni], acc[mi][ni], 0, 0, 0);
    }
}

// ---------------------------------------------------------------------------
// Grouped GEMM. 512 threads = 8 waves (4m x 2n), wave tile 64x32.
// wg -> (record rank r, ntile j) with all 16 ntiles of r on XCD r%8.
// ---------------------------------------------------------------------------
__global__ __launch_bounds__(512, 6)
void cat_gemm_kernel(const float* __restrict__ x,
                     const float* __restrict__ W,
                     const float* __restrict__ bias,
                     const int* __restrict__ recs,
                     float* __restrict__ out) {
    const int wg  = blockIdx.x;
    const int xcd = wg & 7;
    const int pos = wg >> 3;                // 0..127
    const int j   = pos & 15;               // ntile
    const int r   = (pos >> 4) * 8 + xcd;   // record rank 0..63

    const int* rec = recs + r * RSTRIDE;
    const int cat = rec[0];
    const int nb  = rec[1];
    if (nb == 0) return;
    const int n0 = j * BN;

    __shared__ short xs[2][BM * LDK];   // 36.9 KB
    __shared__ short wt[2][BN * LDK];   //  9.2 KB

    const int t    = threadIdx.x;
    const int lane = t & 63;
    const int w    = t >> 6;     // wave 0..7
    const int wm   = w >> 1;     // 0..3
    const int wn   = w & 1;      // 0..1
    const int fl   = lane & 15;
    const int kb   = lane >> 4;

    // X staging: wave w stages batch slot w (rows i*8 + (lane>>3), k (lane&7)*4)
    const int  xrow   = lane >> 3;
    const int  xk4    = (lane & 7) * 4;
    const int  xbatch = rec[2 + w];
    const bool xact   = (w < nb);
    const float* xsrc = x + (size_t)(xbatch * TT + xrow) * DIN + xk4;
    short* xd0 = &xs[0][0] + (w * 32 + xrow) * LDK + xk4;
    short* xd1 = &xs[1][0] + (w * 32 + xrow) * LDK + xk4;

    // W staging: threads 0..127 (waves 0,1); 4x4 register transpose
    const bool wact = (t < 128);
    const int  wk4  = (t & 7) * 4;
    const int  wn4  = ((t >> 3) & 15) * 4;
    const float* wsrc = W + (size_t)cat * (DIN * DH) + (size_t)wk4 * DH + n0 + wn4;

    // MFMA active iff this wave's 64-row band intersects real rows
    const bool mact = (wm * 2 < nb);

    float bv[2];
#pragma unroll
    for (int ni = 0; ni < 2; ++ni)
        bv[ni] = bias[cat * DH + n0 + wn * 32 + ni * 16 + fl];

    f32x4 acc[4][2];
#pragma unroll
    for (int i = 0; i < 4; ++i)
#pragma unroll
        for (int q = 0; q < 2; ++q)
            acc[i][q] = (f32x4){0.f, 0.f, 0.f, 0.f};

    const short* ap0 = &xs[0][0] + (wm * 64 + fl) * LDK + kb * 8;
    const short* ap1 = &xs[1][0] + (wm * 64 + fl) * LDK + kb * 8;
    const short* bp0 = &wt[0][0] + (wn * 32 + fl) * LDK + kb * 8;
    const short* bp1 = &wt[1][0] + (wn * 32 + fl) * LDK + kb * 8;

    // prologue: load K-tile 0
    f32x4 xv[4], wv[4];
    if (xact) {
#pragma unroll
        for (int i = 0; i < 4; ++i)
            xv[i] = *(const f32x4*)(xsrc + (size_t)(i * 8) * DIN);
    }
    if (wact) {
#pragma unroll
        for (int i = 0; i < 4; ++i)
            wv[i] = *(const f32x4*)(wsrc + (size_t)i * DH);
    }

    for (int it = 0; it < NITER; it += 2) {
        gemm_step(xv, wv, xd0, &wt[0][0], ap0, bp0, xsrc, wsrc,
                  xact, wact, mact, wn4, wk4, it, acc);
        gemm_step(xv, wv, xd1, &wt[1][0], ap1, bp1, xsrc, wsrc,
                  xact, wact, mact, wn4, wk4, it + 1, acc);
    }

    // --- epilogue: bias + store rows of real batch slots ---
    if (mact) {
#pragma unroll
        for (int mi = 0; mi < 4; ++mi) {
            const int slot = wm * 2 + (mi >> 1);
            if (slot < nb) {
                const int batch = rec[2 + slot];
                const int rb = (mi & 1) * 16 + kb * 4;
#pragma unroll
                for (int jj = 0; jj < 4; ++jj) {
                    const int trow = rb + jj;
                    float* orow = out + (size_t)(batch * TT + trow) * DH + n0 + wn * 32;
#pragma unroll
                    for (int ni = 0; ni < 2; ++ni)
                        orow[ni * 16 + fl] = acc[mi][ni][jj] + bv[ni];
                }
            }
        }
    }
}

extern "C" void kernel_launch(void* const* d_in, const int* in_sizes, int n_in,
                              void* d_out, int out_size, void* d_ws, size_t ws_size,
                              hipStream_t stream) {
    const float* x       = (const float*)d_in[0];
    const int*   cat_ids = (const int*)d_in[1];
    const float* W       = (const float*)d_in[2];
    const float* bias    = (const float*)d_in[3];
    float*       out     = (float*)d_out;
    int*         recs    = (int*)d_ws;

    hipLaunchKernelGGL(cat_setup_kernel, dim3(1), dim3(256), 0, stream,
                       cat_ids, recs);
    hipLaunchKernelGGL(cat_gemm_kernel, dim3(NRECPAD * NTILES), dim3(512),
                       0, stream, x, W, bias, recs, out);
}

// Round 9
// 145.036 us; speedup vs baseline: 1.2276x; 1.2276x over previous
//
#include <hip/hip_runtime.h>
#include <hip/hip_bf16.h>

// CategorySpecificLinear: out[b,t,h] = sum_d x[b,t,d] * W[cat[b],d,h] + bias[cat[b],h]
// R9: R8 with the spill fixed — __launch_bounds__(512,4) (R8's (512,6) capped
// VGPR at ~85, spilling prefetch regs+acc to scratch: VGPR=40, WRITE_SIZE=287MB).
// 8-batch records (BM=256), BN=64, 512-thread 8-wave blocks, 46KB LDS ->
// 2 blocks/CU = two independent barrier groups for cross-block latency hiding.

#define NCAT 32
#define DIN  1024
#define DH   1024
#define NBATCH 256
#define TT   32
#define NRECPAD 64     // record slots (multiple of 8); sum ceil(cnt/8) <= 60
#define RSTRIDE 12     // ints per record: cat, nb, b0..b7, pad2

#define BM 256
#define BN 64
#define BK 32
#define LDK 36         // LDS row stride in bf16 elems (BK + 4 pad), 18 dwords
#define NITER (DIN / BK)   // 32
#define NTILES (DH / BN)   // 16

typedef __attribute__((ext_vector_type(4))) float f32x4;
typedef __attribute__((ext_vector_type(8))) short bf16x8;
typedef __attribute__((ext_vector_type(4))) short bf16x4;

__device__ inline short f2bf(float f) {
    unsigned u = __builtin_bit_cast(unsigned, f);
    u += 0x7fffu + ((u >> 16) & 1u);
    return (short)(u >> 16);
}

// ---------------------------------------------------------------------------
// Setup: group batches by category into records of <=8, sort by nb desc,
// write to recs[rank]. Rank r runs on XCD r%8 (round-robin deal = LPT-ish).
// ---------------------------------------------------------------------------
__global__ void cat_setup_kernel(const int* __restrict__ cat_ids,
                                 int* __restrict__ recs) {
    __shared__ int cats[NBATCH];
    __shared__ int cnt[NCAT];
    __shared__ int off[NCAT + 1];
    __shared__ int rstart[NCAT + 1];
    __shared__ int blist[NBATCH];
    __shared__ int cbuf[NRECPAD * RSTRIDE];
    __shared__ int nrec_s;
    const int t = threadIdx.x;
    cats[t] = cat_ids[t];
    for (int i = t; i < NRECPAD * RSTRIDE; i += 256) cbuf[i] = 0;
    __syncthreads();
    if (t < NCAT) {
        int c = 0;
        for (int i = 0; i < NBATCH; ++i) c += (cats[i] == t) ? 1 : 0;
        cnt[t] = c;
    }
    __syncthreads();
    if (t == 0) {
        off[0] = 0; rstart[0] = 0;
        for (int c = 0; c < NCAT; ++c) {
            off[c + 1] = off[c] + cnt[c];
            rstart[c + 1] = rstart[c] + (cnt[c] + 7) / 8;
        }
        nrec_s = rstart[NCAT];
    }
    __syncthreads();
    {   // stable scatter: batches grouped by cat
        int c = cats[t], rank = 0;
        for (int i = 0; i < t; ++i) rank += (cats[i] == c) ? 1 : 0;
        blist[off[c] + rank] = t;
    }
    __syncthreads();
    if (t < NCAT) {   // build this cat's records (chunks of 8)
        int base = off[t], rem = cnt[t], k = 0;
        while (rem > 0) {
            int nb = rem < 8 ? rem : 8;
            int* rb = cbuf + (rstart[t] + k) * RSTRIDE;
            rb[0] = t; rb[1] = nb;
            for (int i = 0; i < nb; ++i) rb[2 + i] = blist[base + i];
            for (int i = nb; i < 8; ++i) rb[2 + i] = rb[2];
            base += nb; rem -= nb; ++k;
        }
    }
    __syncthreads();
    for (int i = t; i < NRECPAD * RSTRIDE; i += 256) recs[i] = 0;
    __syncthreads();
    const int nrec = nrec_s;
    if (t < nrec) {   // rank by nb desc (stable), write
        const int mynb = cbuf[t * RSTRIDE + 1];
        int rank = 0;
        for (int i = 0; i < nrec; ++i) {
            const int nbi = cbuf[i * RSTRIDE + 1];
            rank += ((nbi > mynb) || (nbi == mynb && i < t)) ? 1 : 0;
        }
        for (int f = 0; f < RSTRIDE; ++f)
            recs[rank * RSTRIDE + f] = cbuf[t * RSTRIDE + f];
    }
}

// One K-step: convert+stage tile it (predicated), prefetch tile it+1 into the
// same regs, barrier (lgkm-only drain), fragments + 8 MFMA (predicated).
__device__ __forceinline__ void gemm_step(
    f32x4 (&xv)[4], f32x4 (&wv)[4],
    short* xd, short* wd,
    const short* ap, const short* bp,
    const float* xsrc, const float* wsrc,
    bool xact, bool wact, bool mact,
    int wn4, int wk4, int it,
    f32x4 (&acc)[4][2]) {

    if (xact) {
#pragma unroll
        for (int i = 0; i < 4; ++i) {
            bf16x4 q;
            q[0] = f2bf(xv[i][0]);
            q[1] = f2bf(xv[i][1]);
            q[2] = f2bf(xv[i][2]);
            q[3] = f2bf(xv[i][3]);
            *(bf16x4*)(xd + i * 8 * LDK) = q;
        }
    }
    if (wact) {
#pragma unroll
        for (int j = 0; j < 4; ++j) {
            bf16x4 q;
            q[0] = f2bf(wv[0][j]);
            q[1] = f2bf(wv[1][j]);
            q[2] = f2bf(wv[2][j]);
            q[3] = f2bf(wv[3][j]);
            *(bf16x4*)(wd + (wn4 + j) * LDK + wk4) = q;
        }
    }

    if (it + 1 < NITER) {
        const int k0 = (it + 1) * BK;
        if (xact) {
#pragma unroll
            for (int i = 0; i < 4; ++i)
                xv[i] = *(const f32x4*)(xsrc + k0 + (size_t)(i * 8) * DIN);
        }
        if (wact) {
#pragma unroll
            for (int i = 0; i < 4; ++i)
                wv[i] = *(const f32x4*)(wsrc + (size_t)(k0 + i) * DH);
        }
    }

    asm volatile("s_waitcnt lgkmcnt(0)" ::: "memory");
    __builtin_amdgcn_s_barrier();
    asm volatile("" ::: "memory");

    if (mact) {
        bf16x8 af[4], bfr[2];
#pragma unroll
        for (int mi = 0; mi < 4; ++mi)
            af[mi] = *(const bf16x8*)(ap + mi * 16 * LDK);
#pragma unroll
        for (int ni = 0; ni < 2; ++ni)
            bfr[ni] = *(const bf16x8*)(bp + ni * 16 * LDK);
#pragma unroll
        for (int mi = 0; mi < 4; ++mi)
#pragma unroll
            for (int ni = 0; ni < 2; ++ni)
                acc[mi][ni] = __builtin_amdgcn_mfma_f32_16x16x32_bf16(
                    af[mi], bfr[ni], acc[mi][ni], 0, 0, 0);
    }
}

// ---------------------------------------------------------------------------
// Grouped GEMM. 512 threads = 8 waves (4m x 2n), wave tile 64x32.
// wg -> (record rank r, ntile j) with all 16 ntiles of r on XCD r%8.
// ---------------------------------------------------------------------------
__global__ __launch_bounds__(512, 4)
void cat_gemm_kernel(const float* __restrict__ x,
                     const float* __restrict__ W,
                     const float* __restrict__ bias,
                     const int* __restrict__ recs,
                     float* __restrict__ out) {
    const int wg  = blockIdx.x;
    const int xcd = wg & 7;
    const int pos = wg >> 3;                // 0..127
    const int j   = pos & 15;               // ntile
    const int r   = (pos >> 4) * 8 + xcd;   // record rank 0..63

    const int* rec = recs + r * RSTRIDE;
    const int cat = rec[0];
    const int nb  = rec[1];
    if (nb == 0) return;
    const int n0 = j * BN;

    __shared__ short xs[2][BM * LDK];   // 36.9 KB
    __shared__ short wt[2][BN * LDK];   //  9.2 KB

    const int t    = threadIdx.x;
    const int lane = t & 63;
    const int w    = t >> 6;     // wave 0..7
    const int wm   = w >> 1;     // 0..3
    const int wn   = w & 1;      // 0..1
    const int fl   = lane & 15;
    const int kb   = lane >> 4;

    // X staging: wave w stages batch slot w (rows i*8 + (lane>>3), k (lane&7)*4)
    const int  xrow   = lane >> 3;
    const int  xk4    = (lane & 7) * 4;
    const int  xbatch = rec[2 + w];
    const bool xact   = (w < nb);
    const float* xsrc = x + (size_t)(xbatch * TT + xrow) * DIN + xk4;
    short* xd0 = &xs[0][0] + (w * 32 + xrow) * LDK + xk4;
    short* xd1 = &xs[1][0] + (w * 32 + xrow) * LDK + xk4;

    // W staging: threads 0..127 (waves 0,1); 4x4 register transpose
    const bool wact = (t < 128);
    const int  wk4  = (t & 7) * 4;
    const int  wn4  = ((t >> 3) & 15) * 4;
    const float* wsrc = W + (size_t)cat * (DIN * DH) + (size_t)wk4 * DH + n0 + wn4;

    // MFMA active iff this wave's 64-row band intersects real rows
    const bool mact = (wm * 2 < nb);

    float bv[2];
#pragma unroll
    for (int ni = 0; ni < 2; ++ni)
        bv[ni] = bias[cat * DH + n0 + wn * 32 + ni * 16 + fl];

    f32x4 acc[4][2];
#pragma unroll
    for (int i = 0; i < 4; ++i)
#pragma unroll
        for (int q = 0; q < 2; ++q)
            acc[i][q] = (f32x4){0.f, 0.f, 0.f, 0.f};

    const short* ap0 = &xs[0][0] + (wm * 64 + fl) * LDK + kb * 8;
    const short* ap1 = &xs[1][0] + (wm * 64 + fl) * LDK + kb * 8;
    const short* bp0 = &wt[0][0] + (wn * 32 + fl) * LDK + kb * 8;
    const short* bp1 = &wt[1][0] + (wn * 32 + fl) * LDK + kb * 8;

    // prologue: load K-tile 0
    f32x4 xv[4], wv[4];
    if (xact) {
#pragma unroll
        for (int i = 0; i < 4; ++i)
            xv[i] = *(const f32x4*)(xsrc + (size_t)(i * 8) * DIN);
    }
    if (wact) {
#pragma unroll
        for (int i = 0; i < 4; ++i)
            wv[i] = *(const f32x4*)(wsrc + (size_t)i * DH);
    }

    for (int it = 0; it < NITER; it += 2) {
        gemm_step(xv, wv, xd0, &wt[0][0], ap0, bp0, xsrc, wsrc,
                  xact, wact, mact, wn4, wk4, it, acc);
        gemm_step(xv, wv, xd1, &wt[1][0], ap1, bp1, xsrc, wsrc,
                  xact, wact, mact, wn4, wk4, it + 1, acc);
    }

    // --- epilogue: bias + store rows of real batch slots ---
    if (mact) {
#pragma unroll
        for (int mi = 0; mi < 4; ++mi) {
            const int slot = wm * 2 + (mi >> 1);
            if (slot < nb) {
                const int batch = rec[2 + slot];
                const int rb = (mi & 1) * 16 + kb * 4;
#pragma unroll
                for (int jj = 0; jj < 4; ++jj) {
                    const int trow = rb + jj;
                    float* orow = out + (size_t)(batch * TT + trow) * DH + n0 + wn * 32;
#pragma unroll
                    for (int ni = 0; ni < 2; ++ni)
                        orow[ni * 16 + fl] = acc[mi][ni][jj] + bv[ni];
                }
            }
        }
    }
}

extern "C" void kernel_launch(void* const* d_in, const int* in_sizes, int n_in,
                              void* d_out, int out_size, void* d_ws, size_t ws_size,
                              hipStream_t stream) {
    const float* x       = (const float*)d_in[0];
    const int*   cat_ids = (const int*)d_in[1];
    const float* W       = (const float*)d_in[2];
    const float* bias    = (const float*)d_in[3];
    float*       out     = (float*)d_out;
    int*         recs    = (int*)d_ws;

    hipLaunchKernelGGL(cat_setup_kernel, dim3(1), dim3(256), 0, stream,
                       cat_ids, recs);
    hipLaunchKernelGGL(cat_gemm_kernel, dim3(NRECPAD * NTILES), dim3(512),
                       0, stream, x, W, bias, recs, out);
}